// Round 1
// baseline (1362.815 us; speedup 1.0000x reference)
//
#include <hip/hip_runtime.h>
#include <math.h>

// Problem constants
#define NB 64
#define NN 4096
#define ND 256
#define NS 256
#define NK 8
#define NH 512
#define NROW (NB*NN)     // 262144 input rows
#define NSLOT (NB*NK)    // 512 slot rows

typedef unsigned short u16;
typedef unsigned int   u32;
typedef __bf16 bf16x8 __attribute__((ext_vector_type(8)));
typedef float  f32x4  __attribute__((ext_vector_type(4)));

__device__ __forceinline__ float bf2f(u16 u) {
  union { u32 i; float f; } v; v.i = ((u32)u) << 16; return v.f;
}
__device__ __forceinline__ u16 f2bf(float f) {
  union { float f; u32 i; } v; v.f = f;
  u32 x = v.i;
  return (u16)((x + 0x7FFFu + ((x >> 16) & 1u)) >> 16);
}

// ---------------- workspace layout (bytes) ----------------
#define OFF_XBF   0ULL            // 262144*256 bf16 = 134217728
#define OFF_KV    134217728ULL    // 262144*512 bf16 = 268435456
#define OFF_SLOTS 402653184ULL    // 512*256 f32
#define OFF_Q     403177472ULL    // 512*256 f32
#define OFF_ATTN  403701760ULL    // 64*4096*8 f32 = 8388608
#define OFF_UPD   412090368ULL    // 512*256 f32
#define OFF_SUMS  412614656ULL    // 512 f32 (padded 2048)
#define OFF_WC    412616704ULL    // 512*256 bf16
#define OFF_WQT   412878848ULL    // 256*256 f32
#define OFF_WIHT  413140992ULL    // 256*768 f32
#define OFF_WHHT  413927424ULL    // 256*768 f32
#define OFF_W1T   414713856ULL    // 256*512 f32
#define OFF_W2T   415238144ULL    // 512*256 f32  (end 415762432 ~ 397 MiB)

// ---------------- K0: weight prep ----------------
// Wc[j][d] = (j<256 ? Wk[j][d]*S^-0.5 : Wv[j-256][d]) as bf16   (B^T form for GEMM)
// Transposes of the small fp32 weights so per-row kernels read coalesced.
__global__ __launch_bounds__(256) void prep_kernel(
    const float* __restrict__ Wq, const float* __restrict__ Wk, const float* __restrict__ Wv,
    const float* __restrict__ Wih, const float* __restrict__ Whh,
    const float* __restrict__ W1, const float* __restrict__ W2,
    u16* __restrict__ Wc, float* __restrict__ WqT, float* __restrict__ WihT,
    float* __restrict__ WhhT, float* __restrict__ W1T, float* __restrict__ W2T)
{
  int idx = blockIdx.x * 256 + threadIdx.x;   // grid covers 768*256 = 196608
  if (idx < 512*256) {
    int j = idx >> 8, d = idx & 255;
    float w = (j < 256) ? Wk[idx] * 0.0625f : Wv[idx - 65536];
    Wc[idx] = f2bf(w);
    W1T[d*512 + j] = W1[idx];                 // W1 is [512][256]
  }
  if (idx < 256*256) {
    int j = idx >> 8, d = idx & 255;
    WqT[d*256 + j] = Wq[idx];
  }
  if (idx < 768*256) {
    int j = idx >> 8, d = idx & 255;
    WihT[d*768 + j] = Wih[idx];
    WhhT[d*768 + j] = Whh[idx];
  }
  if (idx < 256*512) {
    int j = idx >> 9, h = idx & 511;
    W2T[h*256 + j] = W2[idx];                 // W2 is [256][512]
  }
}

// ---------------- K1: slots init ----------------
__global__ __launch_bounds__(256) void slots_init_kernel(
    const float* __restrict__ noise, const float* __restrict__ mu,
    const float* __restrict__ lsig, float* __restrict__ slots)
{
  int idx = blockIdx.x * 256 + threadIdx.x;   // 131072
  int s = idx & 255;
  slots[idx] = mu[s] + expf(lsig[s]) * noise[idx];
}

// ---------------- K2: LayerNorm(inputs) -> bf16, wave per row ----------------
__global__ __launch_bounds__(256) void ln_cast_kernel(
    const float* __restrict__ x, const float* __restrict__ g, const float* __restrict__ bb,
    u16* __restrict__ out)
{
  int row = blockIdx.x * 4 + (threadIdx.x >> 6);
  int lane = threadIdx.x & 63;
  float4 xv = *(const float4*)(x + (size_t)row * 256 + lane * 4);
  float s  = xv.x + xv.y + xv.z + xv.w;
  float sq = xv.x*xv.x + xv.y*xv.y + xv.z*xv.z + xv.w*xv.w;
  #pragma unroll
  for (int m = 32; m >= 1; m >>= 1) { s += __shfl_xor(s, m, 64); sq += __shfl_xor(sq, m, 64); }
  float mean = s * (1.f/256.f);
  float rstd = rsqrtf(sq * (1.f/256.f) - mean*mean + 1e-5f);
  float4 gv = *(const float4*)(g + lane*4);
  float4 bv = *(const float4*)(bb + lane*4);
  ushort4 o;
  o.x = f2bf((xv.x - mean) * rstd * gv.x + bv.x);
  o.y = f2bf((xv.y - mean) * rstd * gv.y + bv.y);
  o.z = f2bf((xv.z - mean) * rstd * gv.z + bv.z);
  o.w = f2bf((xv.w - mean) * rstd * gv.w + bv.w);
  *(ushort4*)(out + (size_t)row * 256 + lane*4) = o;
}

// ---------------- K3: kv = x_bf @ Wc^T  (M=262144, N=512, K=256) ----------------
// m97-style: 128x128 tile, BK=32, global_load_lds width 16, mfma 16x16x32 bf16.
__global__ __launch_bounds__(256) void gemm_kv_kernel(
    const u16* __restrict__ A, const u16* __restrict__ Bt, u16* __restrict__ C)
{
  __shared__ u16 As[128*32];
  __shared__ u16 Bs[128*32];
  const int tid = threadIdx.x;
  const int lane = tid & 63;
  const int wv = tid >> 6;
  const int bm = blockIdx.x;
  const int bn = blockIdx.y;
  const int wm = (wv & 1) * 64;
  const int wn = (wv >> 1) * 64;

  f32x4 acc[4][4] = {};

  for (int k0 = 0; k0 < 256; k0 += 32) {
    #pragma unroll
    for (int r = 0; r < 2; ++r) {
      int off = ((r*4 + wv) << 10) + lane*16;   // byte offset into the 8KB tile
      int row = off >> 6;
      int col = (off & 63) >> 1;
      const u16* ga = A  + (size_t)(bm*128 + row) * 256 + k0 + col;
      const u16* gb = Bt + (size_t)(bn*128 + row) * 256 + k0 + col;
      __builtin_amdgcn_global_load_lds(
        (const __attribute__((address_space(1))) u32*)ga,
        (__attribute__((address_space(3))) u32*)((char*)As + off), 16, 0, 0);
      __builtin_amdgcn_global_load_lds(
        (const __attribute__((address_space(1))) u32*)gb,
        (__attribute__((address_space(3))) u32*)((char*)Bs + off), 16, 0, 0);
    }
    __syncthreads();
    bf16x8 af[4], bfr[4];
    #pragma unroll
    for (int t4 = 0; t4 < 4; ++t4) {
      af[t4]  = *(const bf16x8*)&As[(wm + t4*16 + (lane & 15)) * 32 + (lane >> 4) * 8];
      bfr[t4] = *(const bf16x8*)&Bs[(wn + t4*16 + (lane & 15)) * 32 + (lane >> 4) * 8];
    }
    #pragma unroll
    for (int mt = 0; mt < 4; ++mt)
      #pragma unroll
      for (int nt = 0; nt < 4; ++nt)
        acc[mt][nt] = __builtin_amdgcn_mfma_f32_16x16x32_bf16(af[mt], bfr[nt], acc[mt][nt], 0, 0, 0);
    __syncthreads();
  }
  const int cr = (lane >> 4) * 4;   // C/D: row = quad*4+reg, col = lane&15 (m89-verified)
  const int cc = lane & 15;
  #pragma unroll
  for (int mt = 0; mt < 4; ++mt)
    #pragma unroll
    for (int nt = 0; nt < 4; ++nt)
      #pragma unroll
      for (int r = 0; r < 4; ++r) {
        size_t row = (size_t)(bm*128 + wm + mt*16 + cr + r);
        int col = bn*128 + wn + nt*16 + cc;
        C[row * 512 + col] = f2bf(acc[mt][nt][r]);
      }
}

// ---------------- K4: q = LN(slots; g_sl,b_sl) @ Wq^T  (2 rows/block) ----------------
__global__ __launch_bounds__(256) void q_kernel(
    const float* __restrict__ slots, const float* __restrict__ gw, const float* __restrict__ bw,
    const float* __restrict__ WqT, float* __restrict__ q)
{
  __shared__ float ln[2][256];
  int t = threadIdx.x, wv = t >> 6, lane = t & 63;
  int base = blockIdx.x * 2;
  if (wv < 2) {
    int row = base + wv;
    float4 xv = *(const float4*)(slots + (size_t)row*256 + lane*4);
    float s  = xv.x + xv.y + xv.z + xv.w;
    float sq = xv.x*xv.x + xv.y*xv.y + xv.z*xv.z + xv.w*xv.w;
    #pragma unroll
    for (int m = 32; m >= 1; m >>= 1) { s += __shfl_xor(s, m, 64); sq += __shfl_xor(sq, m, 64); }
    float mean = s * (1.f/256.f);
    float rstd = rsqrtf(sq * (1.f/256.f) - mean*mean + 1e-5f);
    float4 gv = *(const float4*)(gw + lane*4);
    float4 bv = *(const float4*)(bw + lane*4);
    ln[wv][lane*4+0] = (xv.x - mean)*rstd*gv.x + bv.x;
    ln[wv][lane*4+1] = (xv.y - mean)*rstd*gv.y + bv.y;
    ln[wv][lane*4+2] = (xv.z - mean)*rstd*gv.z + bv.z;
    ln[wv][lane*4+3] = (xv.w - mean)*rstd*gv.w + bv.w;
  }
  __syncthreads();
  float a0 = 0.f, a1 = 0.f;
  for (int d = 0; d < 256; ++d) {
    float w = WqT[d*256 + t];
    a0 += ln[0][d] * w;
    a1 += ln[1][d] * w;
  }
  q[(size_t)base*256 + t]     = a0;
  q[(size_t)(base+1)*256 + t] = a1;
}

// ---------------- K5: logits + softmax(K) + eps + column sums ----------------
// block = (b, chunk of 256 n). thread t owns row n0+t.
__global__ __launch_bounds__(256) void attn_kernel(
    const u16* __restrict__ kv, const float* __restrict__ q,
    float* __restrict__ attn, float* __restrict__ sums)
{
  __shared__ float qs[2048];          // q[b][8][256]
  __shared__ u16 ks[256*66];          // k tile, pad 66 -> 2-way banks (free)
  __shared__ float bsum[8];
  int b = blockIdx.x, chunk = blockIdx.y;
  int t = threadIdx.x, lane = t & 63;
  for (int i = t; i < 2048; i += 256) qs[i] = q[(size_t)b*2048 + i];
  if (t < 8) bsum[t] = 0.f;
  int n0 = chunk * 256;
  float acc[8] = {0,0,0,0,0,0,0,0};
  for (int sc = 0; sc < 256; sc += 64) {
    __syncthreads();
    #pragma unroll
    for (int r = 0; r < 8; ++r) {
      int row = r*32 + (t >> 3);
      int cg = (t & 7) * 8;
      uint4 u = *(const uint4*)(kv + ((size_t)(b*4096 + n0 + row))*512 + sc + cg);
      u32* lp = (u32*)&ks[row*66 + cg];
      lp[0] = u.x; lp[1] = u.y; lp[2] = u.z; lp[3] = u.w;
    }
    __syncthreads();
    for (int ss = 0; ss < 64; ss += 2) {
      u32 pair = *(const u32*)&ks[t*66 + ss];
      float k0v = bf2f((u16)(pair & 0xffffu));
      float k1v = bf2f((u16)(pair >> 16));
      #pragma unroll
      for (int kk = 0; kk < 8; ++kk) {
        float2 qv = *(const float2*)&qs[kk*256 + sc + ss];
        acc[kk] += k0v * qv.x + k1v * qv.y;
      }
    }
  }
  // softmax over 8 slots (per thread, whole row in regs)
  float mx = acc[0];
  #pragma unroll
  for (int kk = 1; kk < 8; ++kk) mx = fmaxf(mx, acc[kk]);
  float se = 0.f;
  #pragma unroll
  for (int kk = 0; kk < 8; ++kk) { acc[kk] = expf(acc[kk] - mx); se += acc[kk]; }
  float inv = 1.f / se;
  #pragma unroll
  for (int kk = 0; kk < 8; ++kk) acc[kk] = acc[kk] * inv + 1e-8f;
  float* ap = attn + ((size_t)(b*4096) + n0 + t) * 8;
  float4 v0 = {acc[0], acc[1], acc[2], acc[3]};
  float4 v1 = {acc[4], acc[5], acc[6], acc[7]};
  *(float4*)ap = v0; *(float4*)(ap + 4) = v1;
  // column sums over n (for the /sum(attn, axis=n) normalization)
  #pragma unroll
  for (int kk = 0; kk < 8; ++kk) {
    float v = acc[kk];
    #pragma unroll
    for (int m = 32; m >= 1; m >>= 1) v += __shfl_xor(v, m, 64);
    if (lane == 0) atomicAdd(&bsum[kk], v);
  }
  __syncthreads();
  if (t < 8) atomicAdd(&sums[b*8 + t], bsum[t]);
}

// ---------------- K6: updates += attn^T @ v  (per 256-n chunk, atomics) ----------------
__global__ __launch_bounds__(256) void upd_kernel(
    const u16* __restrict__ kv, const float* __restrict__ attn, float* __restrict__ upd)
{
  __shared__ float as_[256*8];
  int b = blockIdx.x, chunk = blockIdx.y, t = threadIdx.x;
  int n0 = chunk * 256;
  for (int i = t; i < 2048; i += 256) as_[i] = attn[((size_t)(b*4096) + n0) * 8 + i];
  __syncthreads();
  float acc[8] = {0,0,0,0,0,0,0,0};
  for (int n = 0; n < 256; ++n) {
    float vv = bf2f(kv[((size_t)(b*4096 + n0 + n))*512 + 256 + t]);
    #pragma unroll
    for (int kk = 0; kk < 8; ++kk) acc[kk] += as_[n*8 + kk] * vv;
  }
  #pragma unroll
  for (int kk = 0; kk < 8; ++kk) atomicAdd(&upd[(size_t)(b*8 + kk)*256 + t], acc[kk]);
}

// ---------------- K7: GRU cell, 4 slot-rows per block ----------------
__global__ __launch_bounds__(256) void gru_kernel(
    const float* __restrict__ upd, const float* __restrict__ sums,
    const float* __restrict__ WihT, const float* __restrict__ WhhT,
    const float* __restrict__ bih, const float* __restrict__ bhh,
    float* __restrict__ slots)
{
  __shared__ float xs[4][256], hs[4][256];
  int t = threadIdx.x;
  int base = blockIdx.x * 4;
  #pragma unroll
  for (int g = 0; g < 4; ++g) {
    float inv = 1.0f / sums[base + g];
    xs[g][t] = upd[(size_t)(base+g)*256 + t] * inv;
    hs[g][t] = slots[(size_t)(base+g)*256 + t];
  }
  __syncthreads();
  float ra[4] = {}, za[4] = {}, ia[4] = {}, ha[4] = {};
  for (int d = 0; d < 256; ++d) {
    float wir = WihT[d*768 + t], wiz = WihT[d*768 + 256 + t], win = WihT[d*768 + 512 + t];
    float whr = WhhT[d*768 + t], whz = WhhT[d*768 + 256 + t], whn = WhhT[d*768 + 512 + t];
    #pragma unroll
    for (int g = 0; g < 4; ++g) {
      float x = xs[g][d], h = hs[g][d];
      ra[g] += x*wir + h*whr;
      za[g] += x*wiz + h*whz;
      ia[g] += x*win;
      ha[g] += h*whn;
    }
  }
  float bir = bih[t], biz = bih[256+t], bin = bih[512+t];
  float bhr = bhh[t], bhz = bhh[256+t], bhn = bhh[512+t];
  #pragma unroll
  for (int g = 0; g < 4; ++g) {
    float r  = 1.f/(1.f + expf(-(ra[g] + bir + bhr)));
    float z  = 1.f/(1.f + expf(-(za[g] + biz + bhz)));
    float nn = tanhf(ia[g] + bin + r*(ha[g] + bhn));
    slots[(size_t)(base+g)*256 + t] = (1.f - z)*nn + z*hs[g][t];
  }
}

// ---------------- K8: MLP residual (iters 0,1), 4 rows per block ----------------
__global__ __launch_bounds__(256) void mlp_kernel(
    const float* __restrict__ gw, const float* __restrict__ bw,
    const float* __restrict__ W1T, const float* __restrict__ b1,
    const float* __restrict__ W2T, const float* __restrict__ b2,
    float* __restrict__ slots)
{
  __shared__ float ln[4][256];
  __shared__ float hb[4][512];
  int t = threadIdx.x, wv = t >> 6, lane = t & 63;
  int base = blockIdx.x * 4;
  {
    int row = base + wv;
    float4 xv = *(const float4*)(slots + (size_t)row*256 + lane*4);
    float s  = xv.x + xv.y + xv.z + xv.w;
    float sq = xv.x*xv.x + xv.y*xv.y + xv.z*xv.z + xv.w*xv.w;
    #pragma unroll
    for (int m = 32; m >= 1; m >>= 1) { s += __shfl_xor(s, m, 64); sq += __shfl_xor(sq, m, 64); }
    float mean = s * (1.f/256.f);
    float rstd = rsqrtf(sq * (1.f/256.f) - mean*mean + 1e-5f);
    float4 gv = *(const float4*)(gw + lane*4);
    float4 bv = *(const float4*)(bw + lane*4);
    ln[wv][lane*4+0] = (xv.x - mean)*rstd*gv.x + bv.x;
    ln[wv][lane*4+1] = (xv.y - mean)*rstd*gv.y + bv.y;
    ln[wv][lane*4+2] = (xv.z - mean)*rstd*gv.z + bv.z;
    ln[wv][lane*4+3] = (xv.w - mean)*rstd*gv.w + bv.w;
  }
  __syncthreads();
  float h0[4] = {}, h1[4] = {};
  for (int d = 0; d < 256; ++d) {
    float w0 = W1T[d*512 + t], w1 = W1T[d*512 + 256 + t];
    #pragma unroll
    for (int g = 0; g < 4; ++g) { float l = ln[g][d]; h0[g] += l*w0; h1[g] += l*w1; }
  }
  float bb0 = b1[t], bb1 = b1[256 + t];
  #pragma unroll
  for (int g = 0; g < 4; ++g) {
    hb[g][t]       = fmaxf(h0[g] + bb0, 0.f);
    hb[g][256 + t] = fmaxf(h1[g] + bb1, 0.f);
  }
  __syncthreads();
  float o[4] = {};
  for (int hh = 0; hh < 512; ++hh) {
    float w = W2T[hh*256 + t];
    #pragma unroll
    for (int g = 0; g < 4; ++g) o[g] += hb[g][hh] * w;
  }
  float b2v = b2[t];
  #pragma unroll
  for (int g = 0; g < 4; ++g) {
    size_t idx = (size_t)(base+g)*256 + t;
    slots[idx] = slots[idx] + o[g] + b2v;
  }
}

// ---------------- host ----------------
extern "C" void kernel_launch(void* const* d_in, const int* in_sizes, int n_in,
                              void* d_out, int out_size, void* d_ws, size_t ws_size,
                              hipStream_t stream)
{
  (void)in_sizes; (void)n_in; (void)out_size; (void)ws_size;
  const float* inputs = (const float*)d_in[0];
  const float* noise  = (const float*)d_in[1];
  const float* mu     = (const float*)d_in[2];
  const float* lsig   = (const float*)d_in[3];
  const float* g_in   = (const float*)d_in[4];
  const float* b_in   = (const float*)d_in[5];
  const float* g_sl   = (const float*)d_in[6];
  const float* b_sl   = (const float*)d_in[7];
  const float* g_mlp  = (const float*)d_in[8];
  const float* b_mlp  = (const float*)d_in[9];
  const float* Wq     = (const float*)d_in[10];
  const float* Wk     = (const float*)d_in[11];
  const float* Wv     = (const float*)d_in[12];
  const float* Wih    = (const float*)d_in[13];
  const float* Whh    = (const float*)d_in[14];
  const float* bih    = (const float*)d_in[15];
  const float* bhh    = (const float*)d_in[16];
  const float* W1     = (const float*)d_in[17];
  const float* b1     = (const float*)d_in[18];
  const float* W2     = (const float*)d_in[19];
  const float* b2     = (const float*)d_in[20];

  char* ws = (char*)d_ws;
  u16*   x_bf  = (u16*)  (ws + OFF_XBF);
  u16*   kv    = (u16*)  (ws + OFF_KV);
  float* slots = (float*)(ws + OFF_SLOTS);
  float* q     = (float*)(ws + OFF_Q);
  float* attn  = (float*)(ws + OFF_ATTN);
  float* upd   = (float*)(ws + OFF_UPD);
  float* sums  = (float*)(ws + OFF_SUMS);
  u16*   Wc    = (u16*)  (ws + OFF_WC);
  float* WqT   = (float*)(ws + OFF_WQT);
  float* WihT  = (float*)(ws + OFF_WIHT);
  float* WhhT  = (float*)(ws + OFF_WHHT);
  float* W1T   = (float*)(ws + OFF_W1T);
  float* W2T   = (float*)(ws + OFF_W2T);

  prep_kernel<<<768, 256, 0, stream>>>(Wq, Wk, Wv, Wih, Whh, W1, W2,
                                       Wc, WqT, WihT, WhhT, W1T, W2T);
  slots_init_kernel<<<512, 256, 0, stream>>>(noise, mu, lsig, slots);
  ln_cast_kernel<<<NROW/4, 256, 0, stream>>>(inputs, g_in, b_in, x_bf);
  gemm_kv_kernel<<<dim3(NROW/128, 4), 256, 0, stream>>>(x_bf, Wc, kv);

  for (int it = 0; it < 3; ++it) {
    hipMemsetAsync(upd, 0, 524288 + 2048, stream);   // upd + sums (contiguous)
    q_kernel<<<NSLOT/2, 256, 0, stream>>>(slots, g_sl, b_sl, WqT, q);
    attn_kernel<<<dim3(NB, 16), 256, 0, stream>>>(kv, q, attn, sums);
    upd_kernel<<<dim3(NB, 16), 256, 0, stream>>>(kv, attn, upd);
    gru_kernel<<<NSLOT/4, 256, 0, stream>>>(upd, sums, WihT, WhhT, bih, bhh, slots);
    if (it < 2)
      mlp_kernel<<<NSLOT/4, 256, 0, stream>>>(g_mlp, b_mlp, W1T, b1, W2T, b2, slots);
  }
  hipMemcpyAsync(d_out, slots, (size_t)NSLOT*NS*sizeof(float),
                 hipMemcpyDeviceToDevice, stream);
}

// Round 2
// 1037.779 us; speedup vs baseline: 1.3132x; 1.3132x over previous
//
#include <hip/hip_runtime.h>
#include <math.h>

#define NB 64
#define NN 4096
#define ND 256
#define NS 256
#define NK 8
#define NH 512
#define NROW (NB*NN)
#define NSLOT (NB*NK)
#define EPSA 1e-8f

typedef unsigned short u16;
typedef unsigned int   u32;
typedef __bf16 bf16x8 __attribute__((ext_vector_type(8)));
typedef float  f32x4  __attribute__((ext_vector_type(4)));

__device__ __forceinline__ float bf2f(u16 u) {
  union { u32 i; float f; } v; v.i = ((u32)u) << 16; return v.f;
}
__device__ __forceinline__ u16 f2bf(float f) {
  union { float f; u32 i; } v; v.f = f;
  u32 x = v.i;
  return (u16)((x + 0x7FFFu + ((x >> 16) & 1u)) >> 16);
}

// ---------------- workspace layout (bytes) ----------------
#define OFF_KV     0ULL            // 262144*512 bf16 = 268435456
#define OFF_SLOTS  268435456ULL    // 512*256 f32    = 524288
#define OFF_QBF    268959744ULL    // 512*256 bf16   = 262144
#define OFF_UPDP   269221888ULL    // 1024*8*256 f32 = 8388608
#define OFF_SUMSP  277610496ULL    // 1024*8 f32     = 32768
#define OFF_WC     277643264ULL    // 512*256 bf16   = 262144
#define OFF_WQT    277905408ULL    // 256*256 f32    = 262144
#define OFF_WIHT   278167552ULL    // 256*768 f32    = 786432
#define OFF_WHHT   278953984ULL    // 256*768 f32    = 786432
#define OFF_W1T    279740416ULL    // 256*512 f32    = 524288
#define OFF_W2T    280264704ULL    // 512*256 f32    = 524288  (end ~281 MB)

// ---------------- K0: weight prep (unchanged from r1, proven) ----------------
__global__ __launch_bounds__(256) void prep_kernel(
    const float* __restrict__ Wq, const float* __restrict__ Wk, const float* __restrict__ Wv,
    const float* __restrict__ Wih, const float* __restrict__ Whh,
    const float* __restrict__ W1, const float* __restrict__ W2,
    u16* __restrict__ Wc, float* __restrict__ WqT, float* __restrict__ WihT,
    float* __restrict__ WhhT, float* __restrict__ W1T, float* __restrict__ W2T)
{
  int idx = blockIdx.x * 256 + threadIdx.x;   // 768*256 = 196608
  if (idx < 512*256) {
    int j = idx >> 8, d = idx & 255;
    float w = (j < 256) ? Wk[idx] * 0.0625f : Wv[idx - 65536];
    Wc[idx] = f2bf(w);
    W1T[d*512 + j] = W1[idx];
  }
  if (idx < 256*256) {
    int j = idx >> 8, d = idx & 255;
    WqT[d*256 + j] = Wq[idx];
  }
  if (idx < 768*256) {
    int j = idx >> 8, d = idx & 255;
    WihT[d*768 + j] = Wih[idx];
    WhhT[d*768 + j] = Whh[idx];
  }
  if (idx < 256*512) {
    int j = idx >> 9, h = idx & 511;
    W2T[h*256 + j] = W2[idx];
  }
}

// ---------------- K1: slots init ----------------
__global__ __launch_bounds__(256) void slots_init_kernel(
    const float* __restrict__ noise, const float* __restrict__ mu,
    const float* __restrict__ lsig, float* __restrict__ slots)
{
  int idx = blockIdx.x * 256 + threadIdx.x;
  int s = idx & 255;
  slots[idx] = mu[s] + expf(lsig[s]) * noise[idx];
}

// ---------------- K2: fused LN + kv-projection GEMM ----------------
// Block: 64 rows x all 512 cols. A-tile (LN output, bf16) and B-tiles XOR-chunk-
// swizzled: element (r,k) at halfword r*256 + (((k>>3)^(r&7))<<3) + (k&7).
__global__ __launch_bounds__(256) void lngemm_kernel(
    const float* __restrict__ x, const float* __restrict__ gw, const float* __restrict__ bw,
    const u16* __restrict__ Wc, u16* __restrict__ kv)
{
  __shared__ u16 As[16384];   // 64 x 256 bf16, swizzled
  __shared__ u16 Bs[16384];   // 64 x 256 bf16, swizzled
  const int t = threadIdx.x, w = t >> 6, lane = t & 63;
  const int L15 = lane & 15, q4 = lane >> 4;
  const int blk = blockIdx.x;

  float4 gv = *(const float4*)(gw + lane*4);
  float4 bv = *(const float4*)(bw + lane*4);
  // phase 1: LN 16 rows per wave -> swizzled A-tile
  for (int i = 0; i < 16; ++i) {
    int m = w*16 + i;
    float4 xv = *(const float4*)(x + ((size_t)(blk*64 + m))*256 + lane*4);
    float s  = xv.x + xv.y + xv.z + xv.w;
    float sq = xv.x*xv.x + xv.y*xv.y + xv.z*xv.z + xv.w*xv.w;
    #pragma unroll
    for (int mm = 32; mm >= 1; mm >>= 1) { s += __shfl_xor(s, mm, 64); sq += __shfl_xor(sq, mm, 64); }
    float mean = s * (1.f/256.f);
    float rstd = rsqrtf(sq * (1.f/256.f) - mean*mean + 1e-5f);
    ushort4 o;
    o.x = f2bf((xv.x - mean)*rstd*gv.x + bv.x);
    o.y = f2bf((xv.y - mean)*rstd*gv.y + bv.y);
    o.z = f2bf((xv.z - mean)*rstd*gv.z + bv.z);
    o.w = f2bf((xv.w - mean)*rstd*gv.w + bv.w);
    int swz = (lane >> 1) ^ (m & 7);
    *(ushort4*)&As[m*256 + swz*8 + (lane & 1)*4] = o;
  }
  // phase 2: 8 N-chunks of 64 cols
  for (int nc = 0; nc < 8; ++nc) {
    #pragma unroll
    for (int i = 0; i < 8; ++i) {
      int slot = i*4 + w;
      int g = slot*64 + lane;
      int jr = g >> 5, c = g & 31;
      const u16* src = Wc + ((size_t)(nc*64 + jr))*256 + ((c ^ (jr & 7)) << 3);
      __builtin_amdgcn_global_load_lds(
        (const __attribute__((address_space(1))) u32*)src,
        (__attribute__((address_space(3))) u32*)((char*)Bs + slot*1024 + lane*16), 16, 0, 0);
    }
    __syncthreads();
    f32x4 acc[4] = {};
    #pragma unroll
    for (int ks = 0; ks < 8; ++ks) {
      int swz = (ks*4 + q4) ^ (L15 & 7);
      bf16x8 af = *(const bf16x8*)&As[(w*16 + L15)*256 + swz*8];
      #pragma unroll
      for (int nt = 0; nt < 4; ++nt) {
        bf16x8 bf = *(const bf16x8*)&Bs[(nt*16 + L15)*256 + swz*8];
        acc[nt] = __builtin_amdgcn_mfma_f32_16x16x32_bf16(af, bf, acc[nt], 0, 0, 0);
      }
    }
    __syncthreads();
    #pragma unroll
    for (int nt = 0; nt < 4; ++nt)
      #pragma unroll
      for (int reg = 0; reg < 4; ++reg) {
        size_t row = (size_t)blk*64 + w*16 + q4*4 + reg;
        int col = nc*64 + nt*16 + L15;
        kv[row*512 + col] = f2bf(acc[nt][reg]);
      }
  }
}

// ---------------- K3: q = LN(slots)@Wq^T -> bf16 ----------------
__global__ __launch_bounds__(256) void q_kernel(
    const float* __restrict__ slots, const float* __restrict__ gw, const float* __restrict__ bw,
    const float* __restrict__ WqT, u16* __restrict__ qbf)
{
  __shared__ float ln[2][256];
  int t = threadIdx.x, wv = t >> 6, lane = t & 63;
  int base = blockIdx.x * 2;
  if (wv < 2) {
    int row = base + wv;
    float4 xv = *(const float4*)(slots + (size_t)row*256 + lane*4);
    float s  = xv.x + xv.y + xv.z + xv.w;
    float sq = xv.x*xv.x + xv.y*xv.y + xv.z*xv.z + xv.w*xv.w;
    #pragma unroll
    for (int m = 32; m >= 1; m >>= 1) { s += __shfl_xor(s, m, 64); sq += __shfl_xor(sq, m, 64); }
    float mean = s * (1.f/256.f);
    float rstd = rsqrtf(sq * (1.f/256.f) - mean*mean + 1e-5f);
    float4 gv = *(const float4*)(gw + lane*4);
    float4 bv = *(const float4*)(bw + lane*4);
    ln[wv][lane*4+0] = (xv.x - mean)*rstd*gv.x + bv.x;
    ln[wv][lane*4+1] = (xv.y - mean)*rstd*gv.y + bv.y;
    ln[wv][lane*4+2] = (xv.z - mean)*rstd*gv.z + bv.z;
    ln[wv][lane*4+3] = (xv.w - mean)*rstd*gv.w + bv.w;
  }
  __syncthreads();
  float a0 = 0.f, a1 = 0.f;
  for (int d = 0; d < 256; ++d) {
    float w = WqT[d*256 + t];
    a0 += ln[0][d] * w;
    a1 += ln[1][d] * w;
  }
  qbf[(size_t)base*256 + t]     = f2bf(a0);
  qbf[(size_t)(base+1)*256 + t] = f2bf(a1);
}

// ---------------- K4: fused logits+softmax+PV (MFMA), no atomics ----------------
// grid (64 b, 16 cg); block loops 4 sub-chunks of 64 rows. k-tile and vT share LDS.
__global__ __launch_bounds__(256) void attn_kernel(
    const u16* __restrict__ kv, const u16* __restrict__ qbf,
    float* __restrict__ updp, float* __restrict__ sums_p)
{
  __shared__ u16 tile[16384];       // k: [64][256] swz  |  vT: [256][64] swz (union)
  __shared__ u16 attn_bf[16*72];    // attn^T [slot][n], rows 8..15 garbage
  __shared__ float sums_w[4][8];
  const int b = blockIdx.x, cg = blockIdx.y;
  const int t = threadIdx.x, w = t >> 6, lane = t & 63;
  const int L15 = lane & 15, q4 = lane >> 4;

  if (t < 32) sums_w[t >> 3][t & 7] = 0.f;

  // q B-frags held in registers (8 ksteps x 8 bf16)
  bf16x8 qf[8];
  {
    int slot = (L15 < 8) ? L15 : 7;
    const u16* qp = qbf + ((size_t)b*8 + slot)*256;
    #pragma unroll
    for (int ks = 0; ks < 8; ++ks)
      qf[ks] = *(const bf16x8*)(qp + ks*32 + q4*8);
  }

  f32x4 accp[4] = {};
  for (int cc = 0; cc < 4; ++cc) {
    const int n0 = cg*256 + cc*64;
    // v rows -> registers (coalesced uint4)
    uint4 vr[8];
    #pragma unroll
    for (int j = 0; j < 8; ++j) {
      int idx = j*256 + t;
      int n = idx >> 5, dc = idx & 31;
      vr[j] = *(const uint4*)(kv + ((size_t)(b*4096 + n0 + n))*512 + 256 + dc*8);
    }
    // k-tile -> LDS (swizzled global_load_lds)
    #pragma unroll
    for (int i = 0; i < 8; ++i) {
      int slot = i*4 + w;
      int g = slot*64 + lane;
      int lr = g >> 5, c = g & 31;
      const u16* src = kv + ((size_t)(b*4096 + n0 + lr))*512 + ((c ^ (lr & 7)) << 3);
      __builtin_amdgcn_global_load_lds(
        (const __attribute__((address_space(1))) u32*)src,
        (__attribute__((address_space(3))) u32*)((char*)tile + slot*1024 + lane*16), 16, 0, 0);
    }
    __syncthreads();
    // logits MFMA: wave w does rows 16w..16w+15; cols = slots (0..7 valid)
    f32x4 lg = {};
    #pragma unroll
    for (int ks = 0; ks < 8; ++ks) {
      int swz = (ks*4 + q4) ^ (L15 & 7);
      bf16x8 af = *(const bf16x8*)&tile[(w*16 + L15)*256 + swz*8];
      lg = __builtin_amdgcn_mfma_f32_16x16x32_bf16(af, qf[ks], lg, 0, 0, 0);
    }
    // in-register softmax over slots (lane bits 0..2 = col), rows = q4*4+reg
    float attnv[4], tot = 0.f;
    #pragma unroll
    for (int reg = 0; reg < 4; ++reg) {
      float val = lg[reg];
      float mx = val;
      mx = fmaxf(mx, __shfl_xor(mx, 1, 64));
      mx = fmaxf(mx, __shfl_xor(mx, 2, 64));
      mx = fmaxf(mx, __shfl_xor(mx, 4, 64));
      float e = expf(val - mx);
      float se = e;
      se += __shfl_xor(se, 1, 64);
      se += __shfl_xor(se, 2, 64);
      se += __shfl_xor(se, 4, 64);
      attnv[reg] = e / se + EPSA;
      tot += attnv[reg];
    }
    tot += __shfl_xor(tot, 16, 64);
    tot += __shfl_xor(tot, 32, 64);
    __syncthreads();   // all waves done reading k-tile
    // v transpose -> same LDS (vT [256][64] swizzled)
    #pragma unroll
    for (int j = 0; j < 8; ++j) {
      int idx = j*256 + t;
      int n = idx >> 5, dc = idx & 31;
      u32 words[4] = {vr[j].x, vr[j].y, vr[j].z, vr[j].w};
      #pragma unroll
      for (int e = 0; e < 8; ++e) {
        int d = dc*8 + e;
        int f = (dc + e) & 7;
        int swz = (n >> 3) ^ f;
        tile[d*64 + swz*8 + (n & 7)] = (u16)(words[e >> 1] >> ((e & 1)*16));
      }
    }
    // attn^T -> LDS + col sums
    if (L15 < 8) {
      #pragma unroll
      for (int reg = 0; reg < 4; ++reg)
        attn_bf[L15*72 + w*16 + q4*4 + reg] = f2bf(attnv[reg]);
      if (lane < 8) sums_w[w][lane] += tot;
    }
    __syncthreads();
    // PV MFMA: upd[slot][d] += attn^T @ v ; wave w covers d = 64w..64w+63
    #pragma unroll
    for (int ks = 0; ks < 2; ++ks) {
      bf16x8 paf = *(const bf16x8*)&attn_bf[L15*72 + ks*32 + q4*8];
      #pragma unroll
      for (int nt = 0; nt < 4; ++nt) {
        int d = (w*4 + nt)*16 + L15;
        int swz = (ks*4 + q4) ^ ((d + (d >> 3)) & 7);
        bf16x8 vbf = *(const bf16x8*)&tile[d*64 + swz*8];
        accp[nt] = __builtin_amdgcn_mfma_f32_16x16x32_bf16(paf, vbf, accp[nt], 0, 0, 0);
      }
    }
    __syncthreads();   // PV done before next k-stage overwrites tile
  }
  // store partials (slots = rows q4*4+reg for q4<2)
  float* up = updp + ((size_t)(b*16 + cg))*2048;
  if (q4 < 2) {
    #pragma unroll
    for (int nt = 0; nt < 4; ++nt) {
      int d = (w*4 + nt)*16 + L15;
      #pragma unroll
      for (int reg = 0; reg < 4; ++reg)
        up[(q4*4 + reg)*256 + d] = accp[nt][reg];
    }
  }
  if (t < 8)
    sums_p[(b*16 + cg)*8 + t] = sums_w[0][t] + sums_w[1][t] + sums_w[2][t] + sums_w[3][t];
}

// ---------------- K5: partial-reduce + GRU + (optional) MLP ----------------
__global__ __launch_bounds__(256) void grumlp_kernel(
    const float* __restrict__ updp, const float* __restrict__ sums_p,
    const float* __restrict__ WihT, const float* __restrict__ WhhT,
    const float* __restrict__ bih, const float* __restrict__ bhh,
    const float* __restrict__ gm, const float* __restrict__ bm,
    const float* __restrict__ W1T, const float* __restrict__ b1,
    const float* __restrict__ W2T, const float* __restrict__ b2,
    float* __restrict__ slots, int do_mlp)
{
  __shared__ float xs[4][256], hs[4][256];
  __shared__ float ln[4][256];
  __shared__ float hb[4][512];
  int t = threadIdx.x, w = t >> 6, lane = t & 63;
  int base = blockIdx.x * 4;
  #pragma unroll
  for (int g = 0; g < 4; ++g) {
    int row = base + g;
    int b = row >> 3, s = row & 7;
    float u = 0.f, sm = 0.f;
    for (int c = 0; c < 16; ++c) {
      u  += updp[((size_t)(b*16 + c)*8 + s)*256 + t];
      sm += sums_p[(b*16 + c)*8 + s];
    }
    xs[g][t] = u / sm;
    hs[g][t] = slots[(size_t)row*256 + t];
  }
  __syncthreads();
  float ra[4] = {}, za[4] = {}, ia[4] = {}, ha[4] = {};
  for (int d = 0; d < 256; ++d) {
    float wir = WihT[d*768 + t], wiz = WihT[d*768 + 256 + t], win = WihT[d*768 + 512 + t];
    float whr = WhhT[d*768 + t], whz = WhhT[d*768 + 256 + t], whn = WhhT[d*768 + 512 + t];
    #pragma unroll
    for (int g = 0; g < 4; ++g) {
      float xx = xs[g][d], hh = hs[g][d];
      ra[g] += xx*wir + hh*whr;
      za[g] += xx*wiz + hh*whz;
      ia[g] += xx*win;
      ha[g] += hh*whn;
    }
  }
  float bir = bih[t], biz = bih[256+t], bin = bih[512+t];
  float bhr = bhh[t], bhz = bhh[256+t], bhn = bhh[512+t];
  float nv[4];
  #pragma unroll
  for (int g = 0; g < 4; ++g) {
    float r  = 1.f/(1.f + expf(-(ra[g] + bir + bhr)));
    float z  = 1.f/(1.f + expf(-(za[g] + biz + bhz)));
    float nn = tanhf(ia[g] + bin + r*(ha[g] + bhn));
    nv[g] = (1.f - z)*nn + z*hs[g][t];
  }
  if (!do_mlp) {
    #pragma unroll
    for (int g = 0; g < 4; ++g)
      slots[(size_t)(base+g)*256 + t] = nv[g];
    return;
  }
  #pragma unroll
  for (int g = 0; g < 4; ++g) xs[g][t] = nv[g];
  __syncthreads();
  // LN over new slots: wave w owns row w
  {
    float4 xv = *(const float4*)&xs[w][lane*4];
    float s  = xv.x + xv.y + xv.z + xv.w;
    float sq = xv.x*xv.x + xv.y*xv.y + xv.z*xv.z + xv.w*xv.w;
    #pragma unroll
    for (int m = 32; m >= 1; m >>= 1) { s += __shfl_xor(s, m, 64); sq += __shfl_xor(sq, m, 64); }
    float mean = s * (1.f/256.f);
    float rstd = rsqrtf(sq * (1.f/256.f) - mean*mean + 1e-5f);
    float4 gv = *(const float4*)(gm + lane*4);
    float4 bv = *(const float4*)(bm + lane*4);
    ln[w][lane*4+0] = (xv.x - mean)*rstd*gv.x + bv.x;
    ln[w][lane*4+1] = (xv.y - mean)*rstd*gv.y + bv.y;
    ln[w][lane*4+2] = (xv.z - mean)*rstd*gv.z + bv.z;
    ln[w][lane*4+3] = (xv.w - mean)*rstd*gv.w + bv.w;
  }
  __syncthreads();
  float h0[4] = {}, h1[4] = {};
  for (int d = 0; d < 256; ++d) {
    float w0 = W1T[d*512 + t], w1 = W1T[d*512 + 256 + t];
    #pragma unroll
    for (int g = 0; g < 4; ++g) { float l = ln[g][d]; h0[g] += l*w0; h1[g] += l*w1; }
  }
  float bb0 = b1[t], bb1 = b1[256 + t];
  #pragma unroll
  for (int g = 0; g < 4; ++g) {
    hb[g][t]       = fmaxf(h0[g] + bb0, 0.f);
    hb[g][256 + t] = fmaxf(h1[g] + bb1, 0.f);
  }
  __syncthreads();
  float o[4] = {};
  for (int hh = 0; hh < 512; ++hh) {
    float ww = W2T[hh*256 + t];
    #pragma unroll
    for (int g = 0; g < 4; ++g) o[g] += hb[g][hh] * ww;
  }
  float b2v = b2[t];
  #pragma unroll
  for (int g = 0; g < 4; ++g)
    slots[(size_t)(base+g)*256 + t] = xs[g][t] + o[g] + b2v;
}

// ---------------- host ----------------
extern "C" void kernel_launch(void* const* d_in, const int* in_sizes, int n_in,
                              void* d_out, int out_size, void* d_ws, size_t ws_size,
                              hipStream_t stream)
{
  (void)in_sizes; (void)n_in; (void)out_size; (void)ws_size;
  const float* inputs = (const float*)d_in[0];
  const float* noise  = (const float*)d_in[1];
  const float* mu     = (const float*)d_in[2];
  const float* lsig   = (const float*)d_in[3];
  const float* g_in   = (const float*)d_in[4];
  const float* b_in   = (const float*)d_in[5];
  const float* g_sl   = (const float*)d_in[6];
  const float* b_sl   = (const float*)d_in[7];
  const float* g_mlp  = (const float*)d_in[8];
  const float* b_mlp  = (const float*)d_in[9];
  const float* Wq     = (const float*)d_in[10];
  const float* Wk     = (const float*)d_in[11];
  const float* Wv     = (const float*)d_in[12];
  const float* Wih    = (const float*)d_in[13];
  const float* Whh    = (const float*)d_in[14];
  const float* bih    = (const float*)d_in[15];
  const float* bhh    = (const float*)d_in[16];
  const float* W1     = (const float*)d_in[17];
  const float* b1     = (const float*)d_in[18];
  const float* W2     = (const float*)d_in[19];
  const float* b2     = (const float*)d_in[20];

  char* ws = (char*)d_ws;
  u16*   kv     = (u16*)  (ws + OFF_KV);
  float* slots  = (float*)(ws + OFF_SLOTS);
  u16*   qb     = (u16*)  (ws + OFF_QBF);
  float* updp   = (float*)(ws + OFF_UPDP);
  float* sums_p = (float*)(ws + OFF_SUMSP);
  u16*   Wc     = (u16*)  (ws + OFF_WC);
  float* WqT    = (float*)(ws + OFF_WQT);
  float* WihT   = (float*)(ws + OFF_WIHT);
  float* WhhT   = (float*)(ws + OFF_WHHT);
  float* W1T    = (float*)(ws + OFF_W1T);
  float* W2T    = (float*)(ws + OFF_W2T);

  prep_kernel<<<768, 256, 0, stream>>>(Wq, Wk, Wv, Wih, Whh, W1, W2,
                                       Wc, WqT, WihT, WhhT, W1T, W2T);
  slots_init_kernel<<<512, 256, 0, stream>>>(noise, mu, lsig, slots);
  lngemm_kernel<<<NROW/64, 256, 0, stream>>>(inputs, g_in, b_in, Wc, kv);

  for (int it = 0; it < 3; ++it) {
    q_kernel<<<NSLOT/2, 256, 0, stream>>>(slots, g_sl, b_sl, WqT, qb);
    attn_kernel<<<dim3(NB, 16), 256, 0, stream>>>(kv, qb, updp, sums_p);
    grumlp_kernel<<<NSLOT/4, 256, 0, stream>>>(updp, sums_p, WihT, WhhT, bih, bhh,
                                               g_mlp, b_mlp, W1T, b1, W2T, b2,
                                               slots, (it < 2) ? 1 : 0);
  }
  hipMemcpyAsync(d_out, slots, (size_t)NSLOT*NS*sizeof(float),
                 hipMemcpyDeviceToDevice, stream);
}